// Round 5
// baseline (243.889 us; speedup 1.0000x reference)
//
#include <hip/hip_runtime.h>
#include <stdint.h>

#define NN  2048
#define QPS 8             // float4 quads per lane segment
#define QPR 512           // quads per row
#define WPB 4             // waves per block (256 threads)
#define RPW 8             // rows per wave = 4 pairs

typedef float f32x4 __attribute__((ext_vector_type(4)));

// One WAVE per row via affine-carry suffix scan (math identical to rounds 1-4, PASSED).
// Round-5: NO asm fences, NO global_load_lds -- all ordering is compiler dataflow.
// Input loaded straight to registers (lane owns a contiguous 128-B segment; L2
// serves full lines, HBM traffic stays compulsory). Two rows processed per
// iteration with fully interleaved chains (2x ILP on pass1/scan/pass2 latency).
// LDS is output-staging only (swizzled transpose -> coalesced nontemporal stores).
__global__ __launch_bounds__(256, 2) void ring_givens_scan_kernel(
        const float* __restrict__ x,
        const float* __restrict__ angles,
        float* __restrict__ y,
        int B) {
    __shared__ float4 obuf[WPB][2][QPR];   // 2 output row-buffers per wave, 64 KB/block
    const int lane = threadIdx.x & 63;
    const int wib  = threadIdx.x >> 6;
    float4* const oA = obuf[wib][0];
    float4* const oB = obuf[wib][1];

    // --- per-lane (c,s) in registers: A[q]=(c,s,c,s) j=4q,4q+1; Bq[q] j=4q+2,4q+3 ---
    float4 A[QPS], Bq[QPS];
    {
        const float4* ap4 = (const float4*)(angles + lane * 32);
        #pragma unroll
        for (int q = 0; q < QPS; ++q) {
            float4 av = ap4[q]; float ss, cc;
            sincosf(av.x, &ss, &cc); A[q].x = cc;  A[q].y = ss;
            sincosf(av.y, &ss, &cc); A[q].z = cc;  A[q].w = ss;
            sincosf(av.z, &ss, &cc); Bq[q].x = cc; Bq[q].y = ss;
            sincosf(av.w, &ss, &cc); Bq[q].z = cc; Bq[q].w = ss;
        }
    }
    float sl, cl;                           // (c,s) for k = 2047 (t0 fold)
    sincosf(angles[NN - 1], &sl, &cl);

    // --- hoisted row-independent scan state ---
    float Mseg = 1.0f;
    #pragma unroll
    for (int q = 0; q < QPS; ++q) Mseg *= (A[q].y * A[q].w) * (Bq[q].y * Bq[q].w);
    float Ms[6]; float Mc = Mseg;
    #pragma unroll
    for (int d = 1, st = 0; d < 64; d <<= 1, ++st) {
        Ms[st] = (lane + d < 64) ? Mc : 0.0f;     // predicate folded in
        float Mo = __shfl_down(Mc, d);
        if (lane + d < 64) Mc *= Mo;
    }
    float Mn = __shfl_down(Mc, 1);
    Mn = (lane == 63) ? 1.0f : Mn;                // lane 63 carry = x0 directly

    const int TW   = gridDim.x * WPB;
    const int gwid = blockIdx.x * WPB + wib;

    float4 wAr[QPS], wBr[QPS];
    // --- prologue: load pair 0 straight to regs (lane-contiguous 128-B segment) ---
    {
        const int rA = min(gwid, B - 1);
        const int rB = min(gwid + TW, B - 1);
        const float4* xa = (const float4*)(x + (size_t)rA * NN) + lane * QPS;
        const float4* xb = (const float4*)(x + (size_t)rB * NN) + lane * QPS;
        #pragma unroll
        for (int q = 0; q < QPS; ++q) { wAr[q] = xa[q]; wBr[q] = xb[q]; }
    }

    #pragma unroll
    for (int p = 0; p < RPW / 2; ++p) {
        const int rA = gwid + (2 * p) * TW;
        const int rB = rA + TW;

        // --- ring boundary: x[0], x[2047] via shfl; lane 0 patches t0 ---
        const float x0A = __shfl(wAr[0].x, 0);
        const float xlA = __shfl(wAr[7].w, 63);
        const float x0B = __shfl(wBr[0].x, 0);
        const float xlB = __shfl(wBr[7].w, 63);
        if (lane == 0) {
            wAr[0].x = sl * xlA + cl * x0A;
            wBr[0].x = sl * xlB + cl * x0B;
        }

        // --- pass 1: lane-local U, both rows interleaved (chain = 1 FMA/step) ---
        float UA = 0.0f, UB = 0.0f;
        #pragma unroll
        for (int q = QPS - 1; q >= 0; --q) {
            UA = fmaf(-Bq[q].w, UA, Bq[q].z * wAr[q].w);
            UB = fmaf(-Bq[q].w, UB, Bq[q].z * wBr[q].w);
            UA = fmaf(-Bq[q].y, UA, Bq[q].x * wAr[q].z);
            UB = fmaf(-Bq[q].y, UB, Bq[q].x * wBr[q].z);
            UA = fmaf(-A[q].w,  UA, A[q].z  * wAr[q].y);
            UB = fmaf(-A[q].w,  UB, A[q].z  * wBr[q].y);
            UA = fmaf(-A[q].y,  UA, A[q].x  * wAr[q].x);
            UB = fmaf(-A[q].y,  UB, A[q].x  * wBr[q].x);
        }

        // --- suffix scan, both rows interleaved ---
        #pragma unroll
        for (int d = 1, st = 0; d < 64; d <<= 1, ++st) {
            float UoA = __shfl_down(UA, d);
            float UoB = __shfl_down(UB, d);
            UA = fmaf(Ms[st], UoA, UA);
            UB = fmaf(Ms[st], UoB, UB);
        }
        float UnA = __shfl_down(UA, 1);
        float UnB = __shfl_down(UB, 1);
        UnA = (lane == 63) ? 0.0f : UnA;
        UnB = (lane == 63) ? 0.0f : UnB;
        float aA = fmaf(Mn, x0A, UnA);            // incoming carries
        float aB = fmaf(Mn, x0B, UnB);

        // --- pass 2: emit, quad-assembled swizzled LDS writes (both rows) ---
        const int segq = lane * QPS;
        float eA31, pA0, pA1, pA2, eB31, pB0, pB1, pB2;
        {   // q = 7
            float4 vA = wAr[7], vB = wBr[7];
            eA31 = fmaf(Bq[7].z, aA, Bq[7].w * vA.w);  aA = fmaf(-Bq[7].w, aA, Bq[7].z * vA.w);
            eB31 = fmaf(Bq[7].z, aB, Bq[7].w * vB.w);  aB = fmaf(-Bq[7].w, aB, Bq[7].z * vB.w);
            pA2  = fmaf(Bq[7].x, aA, Bq[7].y * vA.z);  aA = fmaf(-Bq[7].y, aA, Bq[7].x * vA.z);
            pB2  = fmaf(Bq[7].x, aB, Bq[7].y * vB.z);  aB = fmaf(-Bq[7].y, aB, Bq[7].x * vB.z);
            pA1  = fmaf(A[7].z,  aA, A[7].w  * vA.y);  aA = fmaf(-A[7].w,  aA, A[7].z  * vA.y);
            pB1  = fmaf(A[7].z,  aB, A[7].w  * vB.y);  aB = fmaf(-A[7].w,  aB, A[7].z  * vB.y);
            pA0  = fmaf(A[7].x,  aA, A[7].y  * vA.x);  aA = fmaf(-A[7].y,  aA, A[7].x  * vA.x);
            pB0  = fmaf(A[7].x,  aB, A[7].y  * vB.x);  aB = fmaf(-A[7].y,  aB, A[7].x  * vB.x);
        }
        #pragma unroll
        for (int q = QPS - 2; q >= 0; --q) {
            float4 vA = wAr[q], vB = wBr[q];
            float eA3 = fmaf(Bq[q].z, aA, Bq[q].w * vA.w);  aA = fmaf(-Bq[q].w, aA, Bq[q].z * vA.w);
            float eB3 = fmaf(Bq[q].z, aB, Bq[q].w * vB.w);  aB = fmaf(-Bq[q].w, aB, Bq[q].z * vB.w);
            oA[segq + ((q + 1) ^ (lane & 7))] = make_float4(eA3, pA0, pA1, pA2);
            oB[segq + ((q + 1) ^ (lane & 7))] = make_float4(eB3, pB0, pB1, pB2);
            float eA2 = fmaf(Bq[q].x, aA, Bq[q].y * vA.z);  aA = fmaf(-Bq[q].y, aA, Bq[q].x * vA.z);
            float eB2 = fmaf(Bq[q].x, aB, Bq[q].y * vB.z);  aB = fmaf(-Bq[q].y, aB, Bq[q].x * vB.z);
            float eA1 = fmaf(A[q].z,  aA, A[q].w * vA.y);   aA = fmaf(-A[q].w,  aA, A[q].z * vA.y);
            float eB1 = fmaf(A[q].z,  aB, A[q].w * vB.y);   aB = fmaf(-A[q].w,  aB, A[q].z * vB.y);
            float eA0 = fmaf(A[q].x,  aA, A[q].y * vA.x);   aA = fmaf(-A[q].y,  aA, A[q].x * vA.x);
            float eB0 = fmaf(A[q].x,  aB, A[q].y * vB.x);   aB = fmaf(-A[q].y,  aB, A[q].x * vB.x);
            pA0 = eA0; pA1 = eA1; pA2 = eA2;
            pB0 = eB0; pB1 = eB1; pB2 = eB2;
        }
        {
            float prevA = __shfl_up(eA31, 1);
            float prevB = __shfl_up(eB31, 1);
            float s0A = (lane == 0) ? aA : prevA;  // lane0 slot0 = y[0] = final carry
            float s0B = (lane == 0) ? aB : prevB;
            oA[segq + (0 ^ (lane & 7))] = make_float4(s0A, pA0, pA1, pA2);
            oB[segq + (0 ^ (lane & 7))] = make_float4(s0B, pB0, pB1, pB2);
        }

        // --- prefetch next pair into regs (w dead; overlaps transpose-out + next boundary) ---
        if (p + 1 < RPW / 2) {
            const int nA = min(rA + 2 * TW, B - 1);
            const int nB = min(rB + 2 * TW, B - 1);
            const float4* xa = (const float4*)(x + (size_t)nA * NN) + lane * QPS;
            const float4* xb = (const float4*)(x + (size_t)nB * NN) + lane * QPS;
            #pragma unroll
            for (int q = 0; q < QPS; ++q) { wAr[q] = xa[q]; wBr[q] = xb[q]; }
        }

        // --- transpose-out: swizzled LDS reads, coalesced nontemporal stores ---
        if (rA < B) {
            float4* yA4 = (float4*)(y + (size_t)rA * NN);
            #pragma unroll
            for (int t = 0; t < 8; ++t) {
                const int pp = t * 64 + lane;
                float4 v = oA[pp ^ ((lane >> 3) & 7)];
                __builtin_nontemporal_store(*(const f32x4*)&v, (f32x4*)(yA4 + pp));
            }
        }
        if (rB < B) {
            float4* yB4 = (float4*)(y + (size_t)rB * NN);
            #pragma unroll
            for (int t = 0; t < 8; ++t) {
                const int pp = t * 64 + lane;
                float4 v = oB[pp ^ ((lane >> 3) & 7)];
                __builtin_nontemporal_store(*(const f32x4*)&v, (f32x4*)(yB4 + pp));
            }
        }
    }
}

extern "C" void kernel_launch(void* const* d_in, const int* in_sizes, int n_in,
                              void* d_out, int out_size, void* d_ws, size_t ws_size,
                              hipStream_t stream) {
    const float* x      = (const float*)d_in[0];
    const float* angles = (const float*)d_in[1];
    float* y            = (float*)d_out;

    const int B = in_sizes[0] / NN;                        // rows (16384)
    const int total_waves = (B + RPW - 1) / RPW;           // 2048
    const int blocks = (total_waves + WPB - 1) / WPB;      // 512 blocks x 256 thr
    hipLaunchKernelGGL(ring_givens_scan_kernel, dim3(blocks), dim3(256), 0, stream,
                       x, angles, y, B);
}

// Round 6
// 242.754 us; speedup vs baseline: 1.0047x; 1.0047x over previous
//
#include <hip/hip_runtime.h>
#include <stdint.h>

#define NN  2048

// ---------- kernel A: precompute (c,s) table into workspace (once, idempotent) ----------
__global__ void cs_init_kernel(const float* __restrict__ angles, float2* __restrict__ cs) {
    const int i = blockIdx.x * blockDim.x + threadIdx.x;
    if (i < NN) {
        float s, c;
        sincosf(angles[i], &s, &c);
        cs[i] = make_float2(c, s);
    }
}

// ---------- kernel B: one BLOCK-row per iteration, thread t owns elements [8t, 8t+8) ----------
// Affine-carry chain (math identical to rounds 1-5, all PASSED):
//   a_k = c_k*x[k] - s_k*a_{k+1},  y[k+1] = s_k*x[k] + c_k*a_{k+1},  carry into k=2047 is x[0],
//   element 0 consumes t0 = s_2047*x[2047] + c_2047*x[0],  y[0] = final carry.
// 2-level suffix scan: 8-step thread-local map (U,M) -> 6-shfl wave scan -> 4-wave LDS combine.
// All M-side scan state is row-invariant and hoisted to registers; per row only U flows.
// Stores: two aligned float4 per thread (32-B granularity) -> adjacent instrs cover full
// 128-B lines, no LDS transpose. LDS = 8 floats. Target 16 waves/CU.
__global__ __launch_bounds__(256, 4) void ring_rows_kernel(
        const float* __restrict__ x,
        const float2* __restrict__ cs,
        float* __restrict__ y,
        int B) {
    __shared__ float tuLds[4];     // per-wave U totals (per row)
    __shared__ float eeLds[4];     // per-wave edge emission e7 of lane 63 (per row)
    const int tid  = threadIdx.x;
    const int lane = tid & 63;
    const int wv   = tid >> 6;

    // --- per-thread (c,s) for elements 8*tid .. 8*tid+7 (from ws table, L1-hot) ---
    float qc[8], qs[8];
    {
        const float4* cs4 = (const float4*)cs + tid * 4;   // 2 (c,s) pairs per float4
        #pragma unroll
        for (int h = 0; h < 4; ++h) {
            float4 v = cs4[h];
            qc[2*h] = v.x; qs[2*h] = v.y; qc[2*h+1] = v.z; qs[2*h+1] = v.w;
        }
    }
    const float2 csl = cs[NN - 1];              // (c,s) for k = 2047
    const float clv = csl.x, slv = csl.y;

    // --- row-invariant scan state (hoisted) ---
    // thread map M = prod over its 8 steps of (-s_j) = prod s_j (8 factors, even sign)
    float Mt = ((qs[0]*qs[1])*(qs[2]*qs[3])) * ((qs[4]*qs[5])*(qs[6]*qs[7]));
    float Ms[6];
    float Mc = Mt;
    #pragma unroll
    for (int d = 1, st = 0; d < 64; d <<= 1, ++st) {
        Ms[st] = (lane + d < 64) ? Mc : 0.0f;   // predicate folded into multiplier
        float Mo = __shfl_down(Mc, d);
        if (lane + d < 64) Mc *= Mo;
    }
    // Mc = inclusive within-wave suffix M; exclusive version:
    float MexW = __shfl_down(Mc, 1);
    if (lane == 63) MexW = 1.0f;
    const float Tm = __shfl(Mc, 0);             // this wave's total M
    if (lane == 0) tuLds[wv] = Tm;              // share wave M totals once
    __syncthreads();
    const float Tm1 = tuLds[1], Tm2 = tuLds[2], Tm3 = tuLds[3];
    __syncthreads();                            // tuLds reused per-row below
    // cross-wave U-combine coefficients: XU = k1*Tu1 + k2*Tu2 + k3*Tu3 (suffix over waves > wv)
    const float k1 = (wv == 0) ? 1.0f : 0.0f;
    const float k2 = (wv == 0) ? Tm1  : (wv == 1 ? 1.0f : 0.0f);
    const float k3 = (wv == 0) ? Tm1 * Tm2 : (wv == 1 ? Tm2 : (wv == 2 ? 1.0f : 0.0f));
    const float TmAbove = (wv == 0) ? Tm1 * Tm2 * Tm3
                        : (wv == 1) ? Tm2 * Tm3
                        : (wv == 2) ? Tm3 : 1.0f;
    const float Gm = MexW * TmAbove;            // global exclusive M suffix over threads > t

    // --- grid-stride over rows, register prefetch one row ahead ---
    int row = blockIdx.x;
    if (row >= B) return;
    float4 wa, wb; float x0, xl;
    {
        const float* xr = x + (size_t)row * NN;
        wa = *(const float4*)(xr + 8 * tid);
        wb = *(const float4*)(xr + 8 * tid + 4);
        x0 = xr[0]; xl = xr[NN - 1];
    }

    while (true) {
        const int nrow = row + gridDim.x;
        const bool hasNext = (nrow < B);
        float4 waN, wbN; float x0N = 0.0f, xlN = 0.0f;
        if (hasNext) {                            // issue next row's loads NOW (fly under compute)
            const float* xn = x + (size_t)nrow * NN;
            waN = *(const float4*)(xn + 8 * tid);
            wbN = *(const float4*)(xn + 8 * tid + 4);
            x0N = xn[0]; xlN = xn[NN - 1];
        }

        // ring boundary: element 0 consumes t0 instead of x[0]
        if (tid == 0) wa.x = slv * xl + clv * x0;

        // --- pass 1: thread-local U over j = 7..0 (chain = 1 FMA/step) ---
        float U;
        U =      qc[7] * wb.w;
        U = fmaf(-qs[6], U, qc[6] * wb.z);
        U = fmaf(-qs[5], U, qc[5] * wb.y);
        U = fmaf(-qs[4], U, qc[4] * wb.x);
        U = fmaf(-qs[3], U, qc[3] * wa.w);
        U = fmaf(-qs[2], U, qc[2] * wa.z);
        U = fmaf(-qs[1], U, qc[1] * wa.y);
        U = fmaf(-qs[0], U, qc[0] * wa.x);

        // --- wave suffix scan (U only; M hoisted) ---
        #pragma unroll
        for (int d = 1, st = 0; d < 64; d <<= 1, ++st) {
            float Uo = __shfl_down(U, d);
            U = fmaf(Ms[st], Uo, U);
        }
        float UexW = __shfl_down(U, 1);
        if (lane == 63) UexW = 0.0f;
        if (lane == 0) tuLds[wv] = U;             // inclusive wave total Tu
        __syncthreads();
        float XU = k1 * tuLds[1];
        XU = fmaf(k2, tuLds[2], XU);
        XU = fmaf(k3, tuLds[3], XU);
        // incoming carry for this thread (thread 255: UexW=0, XU=0, Gm=1 -> a = x0)
        float a = fmaf(Gm, x0, fmaf(MexW, XU, UexW));

        // --- pass 2: emit, j = 7..0; e_j -> y[8t+j+1] ---
        float e7 = fmaf(qc[7], a, qs[7] * wb.w);  a = fmaf(-qs[7], a, qc[7] * wb.w);
        float e6 = fmaf(qc[6], a, qs[6] * wb.z);  a = fmaf(-qs[6], a, qc[6] * wb.z);
        float e5 = fmaf(qc[5], a, qs[5] * wb.y);  a = fmaf(-qs[5], a, qc[5] * wb.y);
        float e4 = fmaf(qc[4], a, qs[4] * wb.x);  a = fmaf(-qs[4], a, qc[4] * wb.x);
        float e3 = fmaf(qc[3], a, qs[3] * wa.w);  a = fmaf(-qs[3], a, qc[3] * wa.w);
        float e2 = fmaf(qc[2], a, qs[2] * wa.z);  a = fmaf(-qs[2], a, qc[2] * wa.z);
        float e1 = fmaf(qc[1], a, qs[1] * wa.y);  a = fmaf(-qs[1], a, qc[1] * wa.y);
        float e0 = fmaf(qc[0], a, qs[0] * wa.x);  a = fmaf(-qs[0], a, qc[0] * wa.x);

        // --- shift e7 to next thread's slot 0 (wave-internal shfl; wave edges via LDS) ---
        float prev = __shfl_up(e7, 1);
        if (lane == 63) eeLds[wv] = e7;
        __syncthreads();
        if (lane == 0 && wv > 0) prev = eeLds[wv - 1];
        const float s0 = (tid == 0) ? a : prev;   // y[0] = final carry; thread255 e7 (=t0) dropped

        // --- store: two aligned float4 per thread (adjacent instrs cover full lines) ---
        float* yr = y + (size_t)row * NN + 8 * tid;
        *(float4*)(yr)     = make_float4(s0, e0, e1, e2);
        *(float4*)(yr + 4) = make_float4(e3, e4, e5, e6);

        if (!hasNext) break;
        row = nrow;
        wa = waN; wb = wbN; x0 = x0N; xl = xlN;
    }
}

extern "C" void kernel_launch(void* const* d_in, const int* in_sizes, int n_in,
                              void* d_out, int out_size, void* d_ws, size_t ws_size,
                              hipStream_t stream) {
    const float* x      = (const float*)d_in[0];
    const float* angles = (const float*)d_in[1];
    float* y            = (float*)d_out;
    float2* cs          = (float2*)d_ws;           // 2048 * 8 B = 16 KB

    const int B = in_sizes[0] / NN;                // rows (16384)

    hipLaunchKernelGGL(cs_init_kernel, dim3(8), dim3(256), 0, stream, angles, cs);

    const int blocks = 2048;                       // 8 rows/block, 16 waves/CU target
    hipLaunchKernelGGL(ring_rows_kernel, dim3(blocks), dim3(256), 0, stream,
                       x, (const float2*)cs, y, B);
}